// Round 9
// baseline (81.323 us; speedup 1.0000x reference)
//
#include <hip/hip_runtime.h>
#include <hip/hip_bf16.h>

#define NN 4096
#define DD 512

// ---- fused9: 128x128 tiles, 4 waves, fp8 BK=128, 4 K-tiles, single buffer ----
#define TILES 32
#define TRI (TILES*(TILES+1)/2)     // 528
#define NBLK (TILES*TILES + 2*TRI)  // 2080

#define BM 128                      // fallback geometry
#define BK 32
#define LDP 40

typedef __attribute__((ext_vector_type(8))) short short8v;
typedef __attribute__((ext_vector_type(4))) short short4v;
typedef __attribute__((ext_vector_type(4))) float f32x4;
typedef __attribute__((ext_vector_type(4))) int   i32x4;
typedef __attribute__((ext_vector_type(8))) int   i32x8;

static __device__ __forceinline__ short f2bf(float f) {
    union { float f; unsigned u; } a; a.f = f;
    unsigned r = a.u + 0x7FFFu + ((a.u >> 16) & 1u);
    return (short)(r >> 16);
}

// fp32 -> e4m3fn, RNE (software: exact, rounding-mode independent)
static __device__ __forceinline__ unsigned f2e4m3(float f) {
    union { float f; unsigned u; } a; a.f = f;
    unsigned s = (a.u >> 24) & 0x80u;
    float af = fabsf(f);
    if (af < 0.015625f) {                    // |v| < 2^-6 : subnormal (step 2^-9)
        float q = rintf(af * 512.0f);        // RNE; q==8 naturally carries to exp=1
        return s | (unsigned)q;
    }
    if (af >= 440.0f) return s | 0x7Eu;      // clamp to max finite 448
    unsigned u = a.u & 0x7FFFFFFFu;
    u += 0x7FFFFu + ((u >> 20) & 1u);        // RNE into 3-bit mantissa
    unsigned e = u >> 23;                    // >= 121
    return s | ((e - 120u) << 3) | ((u >> 20) & 7u);
}

// e4m3fn -> fp32 (exact)
static __device__ __forceinline__ float e4m3tof(unsigned b) {
    unsigned e = (b >> 3) & 0xFu;
    unsigned m = b & 7u;
    if (e) {
        union { unsigned u; float f; } r;
        r.u = ((b & 0x80u) << 24) | ((e + 120u) << 23) | (m << 20);
        return r.f;
    }
    float v = (float)m * 0.001953125f;       // m * 2^-9
    return (b & 0x80u) ? -v : v;
}

static __device__ __forceinline__ void stage16(const void* g, void* l) {
    __builtin_amdgcn_global_load_lds(
        (const __attribute__((address_space(1))) unsigned int*)g,
        (__attribute__((address_space(3))) unsigned int*)l, 16, 0, 0);
}

static __device__ __forceinline__ void decode_tile(int bid, int& p, int& ti, int& tj, float& w) {
    w = 1.f;
    if (bid < TILES * TILES) {
        p = 2; ti = bid >> 5; tj = bid & (TILES - 1);
    } else {
        int u = bid - TILES * TILES;
        p = 0;
        if (u >= TRI) { p = 1; u -= TRI; }
        int a = 0;
        while (u >= TILES - a) { u -= TILES - a; ++a; }
        ti = a; tj = a + u;
        if (ti != tj) w = 2.f;
    }
}

// ---------- prep9: fp32 -> e4m3 ws + row norms OF THE QUANTIZED data ----------
__global__ void prep9_kernel(const float* __restrict__ x, const float* __restrict__ y,
                             unsigned char* __restrict__ bx, unsigned char* __restrict__ by,
                             float* __restrict__ nx, float* __restrict__ ny) {
    int wid  = (blockIdx.x * blockDim.x + threadIdx.x) >> 6;   // 0..8191, one wave per row
    int lane = threadIdx.x & 63;
    bool isx = wid < NN;
    const float* src = isx ? x : y;
    unsigned char* dst = isx ? bx : by;
    int row = wid & (NN - 1);
    const float4* p = (const float4*)(src + (size_t)row * DD);
    float4 v0 = p[lane * 2];
    float4 v1 = p[lane * 2 + 1];
    float vals[8] = { v0.x, v0.y, v0.z, v0.w, v1.x, v1.y, v1.z, v1.w };
    unsigned lo = 0, hi = 0;
    float s = 0.f;
    #pragma unroll
    for (int i = 0; i < 8; ++i) {
        unsigned b = f2e4m3(vals[i]);
        float d = e4m3tof(b);
        s += d * d;
        if (i < 4) lo |= b << (8 * i); else hi |= b << (8 * (i - 4));
    }
    unsigned long long packed = (unsigned long long)lo | ((unsigned long long)hi << 32);
    *(unsigned long long*)(dst + (size_t)row * DD + lane * 8) = packed;
    #pragma unroll
    for (int off = 32; off > 0; off >>= 1) s += __shfl_down(s, off);
    if (lane == 0) (isx ? nx : ny)[row] = s;
}

// ---------- fused9 ----------
// LDS per matrix: [128 rows][8 chunks of 16B] (128B rows), stored at
// pos = chunk ^ (row & 7)  — identical involution to fused8 (measured 0 conflicts).
__global__ void __launch_bounds__(256)
fused9_kernel(const unsigned char* __restrict__ bx, const unsigned char* __restrict__ by,
              const float* __restrict__ nx, const float* __restrict__ ny,
              float* __restrict__ out) {
    __shared__ __align__(16) unsigned char As[128 * 128];   // 16 KiB
    __shared__ __align__(16) unsigned char Bs[128 * 128];   // 16 KiB
    __shared__ float wsum[4];

    int p, ti, tj; float w;
    decode_tile(blockIdx.x, p, ti, tj, w);

    const unsigned char* PB = (p == 1) ? by : bx;
    const unsigned char* QB = (p == 0) ? bx : by;
    const float*  NA = (p == 1) ? ny : nx;
    const float*  NB = (p == 0) ? nx : ny;

    const int t    = threadIdx.x;
    const int lane = t & 63;
    const int wv   = t >> 6;          // 0..3
    const int wm   = wv >> 1, wn = wv & 1;
    const int fr   = lane & 15;
    const int ch   = lane >> 4;       // 0..3 -> lane's 32B k-block index

    const unsigned char* Ag = PB + (size_t)ti * 128 * DD;
    const unsigned char* Bg = QB + (size_t)tj * 128 * DD;

    // staging: dest linear (wave base + lane*16); source chunk inverse-swizzled
    const int sc16 = ((lane & 7) ^ ((lane >> 3) & 7)) * 16;   // byte offset

    f32x4 acc[4][4];
    #pragma unroll
    for (int m = 0; m < 4; ++m)
        #pragma unroll
        for (int n = 0; n < 4; ++n)
            acc[m][n] = (f32x4){0.f, 0.f, 0.f, 0.f};

#define STAGE9(kt) do {                                                        \
        _Pragma("unroll")                                                      \
        for (int i_ = 0; i_ < 4; ++i_) {                                       \
            int row_ = i_ * 32 + wv * 8 + (lane >> 3);                         \
            stage16(Ag + (size_t)row_ * DD + (kt) * 128 + sc16,                \
                    &As[i_ * 4096 + wv * 1024 + lane * 16]);                   \
            stage16(Bg + (size_t)row_ * DD + (kt) * 128 + sc16,                \
                    &Bs[i_ * 4096 + wv * 1024 + lane * 16]);                   \
        }                                                                      \
    } while (0)

    STAGE9(0);
    __syncthreads();

    const int pa0 = ((2 * ch)     ^ (fr & 7)) * 16;   // swizzled pos of chunk 2c
    const int pa1 = ((2 * ch + 1) ^ (fr & 7)) * 16;   // swizzled pos of chunk 2c+1

    #pragma unroll
    for (int kt = 0; kt < 4; ++kt) {
        // 1) read fragments: lane needs row (l&15), k = (l>>4)*32..+32 (= its MX block)
        i32x8 af[4], bf[4];
        #pragma unroll
        for (int m = 0; m < 4; ++m) {
            int rb = (wm * 64 + m * 16 + fr) * 128;
            i32x4 lo = *(const i32x4*)&As[rb + pa0];
            i32x4 hi = *(const i32x4*)&As[rb + pa1];
            af[m] = __builtin_shufflevector(lo, hi, 0, 1, 2, 3, 4, 5, 6, 7);
        }
        #pragma unroll
        for (int n = 0; n < 4; ++n) {
            int rb = (wn * 64 + n * 16 + fr) * 128;
            i32x4 lo = *(const i32x4*)&Bs[rb + pa0];
            i32x4 hi = *(const i32x4*)&Bs[rb + pa1];
            bf[n] = __builtin_shufflevector(lo, hi, 0, 1, 2, 3, 4, 5, 6, 7);
        }
        __syncthreads();                 // all waves done reading this buffer

        // 2) issue next-tile staging (overlaps MFMA below)
        if (kt + 1 < 4) STAGE9(kt + 1);

        // 3) MFMA cluster: fp8 x fp8, uniform scale 1.0 (E8M0 0x7F in all bytes)
        __builtin_amdgcn_s_setprio(1);
        #pragma unroll
        for (int m = 0; m < 4; ++m)
            #pragma unroll
            for (int n = 0; n < 4; ++n)
                acc[m][n] = __builtin_amdgcn_mfma_scale_f32_16x16x128_f8f6f4(
                    af[m], bf[n], acc[m][n], 0, 0, 0, 0x7F7F7F7F, 0, 0x7F7F7F7F);
        __builtin_amdgcn_s_setprio(0);

        // 4) drain staging + swap-free single buffer
        __syncthreads();
    }
#undef STAGE9

    // ---- epilogue: C layout shape-determined (same as fused8, verified) ----
    float nbv[4];
    #pragma unroll
    for (int n = 0; n < 4; ++n)
        nbv[n] = NB[tj * 128 + wn * 64 + n * 16 + fr];
    const int rbase = ((lane >> 4) << 2);

    float local = 0.f;
    #pragma unroll
    for (int m = 0; m < 4; ++m) {
        float4 na4 = *(const float4*)(&NA[ti * 128 + wm * 64 + m * 16 + rbase]);
        float nav[4] = { na4.x, na4.y, na4.z, na4.w };
        #pragma unroll
        for (int n = 0; n < 4; ++n) {
            #pragma unroll
            for (int rr = 0; rr < 4; ++rr) {
                int gr = ti * 128 + wm * 64 + m * 16 + rbase + rr;
                int gc = tj * 128 + wn * 64 + n * 16 + fr;
                float g  = acc[m][n][rr];
                float d2 = fmaxf(nav[rr] + nbv[n] - 2.f * g, 0.f);
                float e  = __expf(-d2);
                if (p == 2) {
                    float diff = g - ((gr == gc) ? 1.f : 0.f);
                    local += diff * diff - 2.f * e;
                } else {
                    local += w * e;
                }
            }
        }
    }
    #pragma unroll
    for (int off = 32; off > 0; off >>= 1) local += __shfl_down(local, off);
    if (lane == 0) wsum[wv] = local;
    __syncthreads();
    if (t == 0) {
        float s = (wsum[0] + wsum[1]) + (wsum[2] + wsum[3]);
        atomicAdd(out, s * (1.f / ((float)NN * (float)NN)));
    }
}

// ---------- fallback path (round-1, used only if ws too small) ----------
__global__ void norms_kernel(const float* __restrict__ x, const float* __restrict__ y,
                             float* __restrict__ nx, float* __restrict__ ny) {
    int wid  = (blockIdx.x * blockDim.x + threadIdx.x) >> 6;
    int lane = threadIdx.x & 63;
    const float* src = (wid < NN) ? x : y;
    int row = wid & (NN - 1);
    const float4* p = (const float4*)(src + (size_t)row * DD);
    float s = 0.f;
    #pragma unroll
    for (int i = 0; i < 2; ++i) {
        float4 v = p[lane + 64 * i];
        s += v.x * v.x + v.y * v.y + v.z * v.z + v.w * v.w;
    }
    #pragma unroll
    for (int off = 32; off > 0; off >>= 1) s += __shfl_down(s, off);
    if (lane == 0) ((wid < NN) ? nx : ny)[row] = s;
}

__global__ void __launch_bounds__(256)
fused_kernel(const float* __restrict__ x, const float* __restrict__ y,
             const float* __restrict__ nx, const float* __restrict__ ny,
             float* __restrict__ out) {
    __shared__ __align__(16) short As[BM * LDP];
    __shared__ __align__(16) short Bs[BM * LDP];
    __shared__ float wsum[4];

    int p, ti, tj; float w;
    decode_tile(blockIdx.x, p, ti, tj, w);
    const float* P  = (p == 1) ? y  : x;
    const float* Q  = (p == 0) ? x  : y;
    const float* NA = (p == 1) ? ny : nx;
    const float* NB = (p == 0) ? nx : ny;

    const int t    = threadIdx.x;
    const int lane = t & 63;
    const int wvid = t >> 6;
    const int wm = wvid >> 1, wn = wvid & 1;

    f32x4 acc[4][4];
    #pragma unroll
    for (int m = 0; m < 4; ++m)
        #pragma unroll
        for (int n = 0; n < 4; ++n)
            acc[m][n] = (f32x4){0.f, 0.f, 0.f, 0.f};

    const int srow = t >> 3;
    const int scol = (t & 7) * 4;
    const size_t baseA = (size_t)(ti * BM) * DD;
    const size_t baseB = (size_t)(tj * BM) * DD;

    for (int kt = 0; kt < DD; kt += BK) {
        #pragma unroll
        for (int s = 0; s < 4; ++s) {
            int r = s * 32 + srow;
            float4 va = *(const float4*)(P + baseA + (size_t)r * DD + kt + scol);
            float4 vb = *(const float4*)(Q + baseB + (size_t)r * DD + kt + scol);
            short4v ha = { f2bf(va.x), f2bf(va.y), f2bf(va.z), f2bf(va.w) };
            short4v hb = { f2bf(vb.x), f2bf(vb.y), f2bf(vb.z), f2bf(vb.w) };
            *(short4v*)(&As[r * LDP + scol]) = ha;
            *(short4v*)(&Bs[r * LDP + scol]) = hb;
        }
        __syncthreads();

        short8v af[4], bfr[4];
        const int kc = (lane >> 4) * 8;
        #pragma unroll
        for (int m = 0; m < 4; ++m)
            af[m] = *(const short8v*)(&As[(wm * 64 + m * 16 + (lane & 15)) * LDP + kc]);
        #pragma unroll
        for (int n = 0; n < 4; ++n)
            bfr[n] = *(const short8v*)(&Bs[(wn * 64 + n * 16 + (lane & 15)) * LDP + kc]);
        #pragma unroll
        for (int m = 0; m < 4; ++m)
            #pragma unroll
            for (int n = 0; n < 4; ++n)
                acc[m][n] = __builtin_amdgcn_mfma_f32_16x16x32_bf16(af[m], bfr[n], acc[m][n], 0, 0, 0);
        __syncthreads();
    }

    float local = 0.f;
    #pragma unroll
    for (int m = 0; m < 4; ++m) {
        #pragma unroll
        for (int n = 0; n < 4; ++n) {
            #pragma unroll
            for (int r = 0; r < 4; ++r) {
                int row = wm * 64 + m * 16 + ((lane >> 4) << 2) + r;
                int col = wn * 64 + n * 16 + (lane & 15);
                int gr = ti * BM + row, gc = tj * BM + col;
                float g  = acc[m][n][r];
                float d2 = fmaxf(NA[gr] + NB[gc] - 2.f * g, 0.f);
                float e  = __expf(-d2);
                if (p == 2) {
                    float diff = g - ((gr == gc) ? 1.f : 0.f);
                    local += diff * diff - 2.f * e;
                } else {
                    local += w * e;
                }
            }
        }
    }
    #pragma unroll
    for (int off = 32; off > 0; off >>= 1) local += __shfl_down(local, off);
    if (lane == 0) wsum[wvid] = local;
    __syncthreads();
    if (t == 0) {
        float s = (wsum[0] + wsum[1]) + (wsum[2] + wsum[3]);
        atomicAdd(out, s * (1.f / ((float)NN * (float)NN)));
    }
}

extern "C" void kernel_launch(void* const* d_in, const int* in_sizes, int n_in,
                              void* d_out, int out_size, void* d_ws, size_t ws_size,
                              hipStream_t stream) {
    const float* x = (const float*)d_in[0];
    const float* y = (const float*)d_in[1];
    float* out = (float*)d_out;

    hipMemsetAsync(d_out, 0, sizeof(float), stream);

    const size_t need = (size_t)2 * NN * DD + (size_t)2 * NN * sizeof(float);  // 4 MB + 32 KB
    if (ws_size >= need) {
        unsigned char* bx = (unsigned char*)d_ws;
        unsigned char* by = bx + (size_t)NN * DD;
        float* nx = (float*)(by + (size_t)NN * DD);
        float* ny = nx + NN;
        prep9_kernel<<<dim3(2048), dim3(256), 0, stream>>>(x, y, bx, by, nx, ny);
        fused9_kernel<<<dim3(NBLK), dim3(256), 0, stream>>>(bx, by, nx, ny, out);
    } else {
        float* nx = (float*)d_ws;
        float* ny = nx + NN;
        norms_kernel<<<dim3(2048), dim3(256), 0, stream>>>(x, y, nx, ny);
        fused_kernel<<<dim3(NBLK), dim3(256), 0, stream>>>(x, y, nx, ny, out);
    }
}

// Round 10
// 76.261 us; speedup vs baseline: 1.0664x; 1.0664x over previous
//
#include <hip/hip_runtime.h>
#include <hip/hip_bf16.h>

#define NN 4096
#define DD 512
#define NKT 16                      // DD/32 K-steps

// ---- fused10: 128x128 tiles, 4 waves, BK=32, TRIPLE buffer, counted vmcnt ----
#define TILES 32
#define TRI (TILES*(TILES+1)/2)     // 528
#define NBLK (TILES*TILES + 2*TRI)  // 2080
#define BUFU 8192                   // ushorts per buffer (A 4096 + B 4096 = 16 KB)

#define BM 128                      // fallback geometry
#define BK 32
#define LDP 40

typedef __attribute__((ext_vector_type(8))) short short8v;
typedef __attribute__((ext_vector_type(4))) short short4v;
typedef __attribute__((ext_vector_type(4))) float f32x4;

static __device__ __forceinline__ short f2bf(float f) {
    union { float f; unsigned u; } a; a.f = f;
    unsigned r = a.u + 0x7FFFu + ((a.u >> 16) & 1u);
    return (short)(r >> 16);
}

static __device__ __forceinline__ void stage16(const void* g, void* l) {
    __builtin_amdgcn_global_load_lds(
        (const __attribute__((address_space(1))) unsigned int*)g,
        (__attribute__((address_space(3))) unsigned int*)l, 16, 0, 0);
}

static __device__ __forceinline__ void decode_tile(int bid, int& p, int& ti, int& tj, float& w) {
    w = 1.f;
    if (bid < TILES * TILES) {
        p = 2; ti = bid >> 5; tj = bid & (TILES - 1);
    } else {
        int u = bid - TILES * TILES;
        p = 0;
        if (u >= TRI) { p = 1; u -= TRI; }
        int a = 0;
        while (u >= TILES - a) { u -= TILES - a; ++a; }
        ti = a; tj = a + u;
        if (ti != tj) w = 2.f;
    }
}

// ---------- prep: fp32 -> bf16 ws + row norms; also zeroes the output ----------
__global__ void prep_kernel(const float* __restrict__ x, const float* __restrict__ y,
                            ushort* __restrict__ bx, ushort* __restrict__ by,
                            float* __restrict__ nx, float* __restrict__ ny,
                            float* __restrict__ out) {
    if (blockIdx.x == 0 && threadIdx.x == 0) *out = 0.f;   // fold memset into prep
    int wid  = (blockIdx.x * blockDim.x + threadIdx.x) >> 6;   // 0..8191
    int lane = threadIdx.x & 63;
    bool isx = wid < NN;
    const float* src = isx ? x : y;
    ushort* dst = isx ? bx : by;
    int row = wid & (NN - 1);
    const float4* p = (const float4*)(src + (size_t)row * DD);
    float s = 0.f;
    #pragma unroll
    for (int i = 0; i < 2; ++i) {
        float4 v = p[lane + 64 * i];
        s += v.x * v.x + v.y * v.y + v.z * v.z + v.w * v.w;
        short4v h = { f2bf(v.x), f2bf(v.y), f2bf(v.z), f2bf(v.w) };
        *(short4v*)(dst + (size_t)row * DD + 4 * (lane + 64 * i)) = h;
    }
    #pragma unroll
    for (int off = 32; off > 0; off >>= 1) s += __shfl_down(s, off);
    if (lane == 0) (isx ? nx : ny)[row] = s;
}

// ---------- fused10 ----------
// LDS per matrix per buffer: [128 rows][4 chunks of 16B] (64B rows), stored at
// pos = c ^ ((row>>1)&3) — the round-3/5 verified involution (measured 0 conflicts).
__global__ void __launch_bounds__(256)
fused10_kernel(const ushort* __restrict__ bx, const ushort* __restrict__ by,
               const float* __restrict__ nx, const float* __restrict__ ny,
               float* __restrict__ out) {
    __shared__ __align__(16) ushort lds[3 * BUFU];   // 48 KiB
    __shared__ float wsum[4];

    int p, ti, tj; float w;
    decode_tile(blockIdx.x, p, ti, tj, w);

    const ushort* PB = (p == 1) ? by : bx;
    const ushort* QB = (p == 0) ? bx : by;
    const float*  NA = (p == 1) ? ny : nx;
    const float*  NB = (p == 0) ? nx : ny;

    const int t    = threadIdx.x;
    const int lane = t & 63;
    const int wv   = t >> 6;          // 0..3
    const int wm   = wv >> 1, wn = wv & 1;
    const int fr   = lane & 15;

    // verified staging + read swizzle (rounds 3/5: 0 conflicts)
    const int srow = lane >> 2;                               // row within 16-row seg
    const int scol = ((lane & 3) ^ ((lane >> 3) & 3)) * 8;    // inverse-swz source col
    const int cbs  = (((lane >> 4) ^ ((lane >> 1) & 3))) * 8; // swizzled read col

    const ushort* Ag = PB + (size_t)ti * 128 * DD;
    const ushort* Bg = QB + (size_t)tj * 128 * DD;

    f32x4 acc[4][4];
    #pragma unroll
    for (int m = 0; m < 4; ++m)
        #pragma unroll
        for (int n = 0; n < 4; ++n)
            acc[m][n] = (f32x4){0.f, 0.f, 0.f, 0.f};

#define STAGE10(kt, buf) do {                                                  \
        ushort* D_ = lds + (buf) * BUFU;                                       \
        _Pragma("unroll")                                                      \
        for (int i_ = 0; i_ < 2; ++i_) {                                       \
            int s_ = wv * 2 + i_;                                              \
            stage16(Ag + (size_t)(s_ * 16 + srow) * DD + (kt) * BK + scol,     \
                    D_ + s_ * 512);                                            \
            stage16(Bg + (size_t)(s_ * 16 + srow) * DD + (kt) * BK + scol,     \
                    D_ + 4096 + s_ * 512);                                     \
        }                                                                      \
    } while (0)

    // prologue: tiles 0 and 1 in flight (8 outstanding loads/thread)
    STAGE10(0, 0);
    STAGE10(1, 1);

    #pragma unroll
    for (int kt = 0; kt < NKT; ++kt) {
        const int bR = kt % 3;
        // 1) issue prefetch of kt+2 into buffer (kt+2)%3 (read there at step kt-1, done)
        if (kt + 2 < NKT) {
            STAGE10(kt + 2, (kt + 2) % 3);
            asm volatile("s_waitcnt vmcnt(8)" ::: "memory");   // tile kt certified
        } else if (kt + 2 == NKT) {
            asm volatile("s_waitcnt vmcnt(4)" ::: "memory");   // tile kt certified
        } else {
            asm volatile("s_waitcnt vmcnt(0)" ::: "memory");   // last tile certified
        }
        __builtin_amdgcn_s_barrier();            // all waves certified -> tile kt readable

        // 2) read fragments of tile kt
        const ushort* LA = lds + bR * BUFU;
        const ushort* LB = LA + 4096;
        short8v af[4], bf[4];
        #pragma unroll
        for (int m = 0; m < 4; ++m)
            af[m] = *(const short8v*)(&LA[(wm * 64 + m * 16 + fr) * BK + cbs]);
        #pragma unroll
        for (int n = 0; n < 4; ++n)
            bf[n] = *(const short8v*)(&LB[(wn * 64 + n * 16 + fr) * BK + cbs]);

        // 3) MFMA cluster
        __builtin_amdgcn_s_setprio(1);
        #pragma unroll
        for (int m = 0; m < 4; ++m)
            #pragma unroll
            for (int n = 0; n < 4; ++n)
                acc[m][n] = __builtin_amdgcn_mfma_f32_16x16x32_bf16(af[m], bf[n], acc[m][n], 0, 0, 0);
        __builtin_amdgcn_s_setprio(0);

        // 4) reads of buffer bR complete -> next step may overwrite it
        __builtin_amdgcn_s_barrier();
    }
#undef STAGE10

    // ---- epilogue (fused8's verified layout) ----
    float nbv[4];
    #pragma unroll
    for (int n = 0; n < 4; ++n)
        nbv[n] = NB[tj * 128 + wn * 64 + n * 16 + fr];
    const int rbase = ((lane >> 4) << 2);

    float local = 0.f;
    #pragma unroll
    for (int m = 0; m < 4; ++m) {
        float4 na4 = *(const float4*)(&NA[ti * 128 + wm * 64 + m * 16 + rbase]);
        float nav[4] = { na4.x, na4.y, na4.z, na4.w };
        #pragma unroll
        for (int n = 0; n < 4; ++n) {
            #pragma unroll
            for (int rr = 0; rr < 4; ++rr) {
                int gr = ti * 128 + wm * 64 + m * 16 + rbase + rr;
                int gc = tj * 128 + wn * 64 + n * 16 + fr;
                float g  = acc[m][n][rr];
                float d2 = fmaxf(nav[rr] + nbv[n] - 2.f * g, 0.f);
                float e  = __expf(-d2);
                if (p == 2) {
                    float diff = g - ((gr == gc) ? 1.f : 0.f);
                    local += diff * diff - 2.f * e;
                } else {
                    local += w * e;
                }
            }
        }
    }
    #pragma unroll
    for (int off = 32; off > 0; off >>= 1) local += __shfl_down(local, off);
    if (lane == 0) wsum[wv] = local;
    __syncthreads();
    if (t == 0) {
        float s = (wsum[0] + wsum[1]) + (wsum[2] + wsum[3]);
        atomicAdd(out, s * (1.f / ((float)NN * (float)NN)));
    }
}

// ---------- fallback path (round-1, used only if ws too small) ----------
__global__ void norms_kernel(const float* __restrict__ x, const float* __restrict__ y,
                             float* __restrict__ nx, float* __restrict__ ny) {
    int wid  = (blockIdx.x * blockDim.x + threadIdx.x) >> 6;
    int lane = threadIdx.x & 63;
    const float* src = (wid < NN) ? x : y;
    int row = wid & (NN - 1);
    const float4* p = (const float4*)(src + (size_t)row * DD);
    float s = 0.f;
    #pragma unroll
    for (int i = 0; i < 2; ++i) {
        float4 v = p[lane + 64 * i];
        s += v.x * v.x + v.y * v.y + v.z * v.z + v.w * v.w;
    }
    #pragma unroll
    for (int off = 32; off > 0; off >>= 1) s += __shfl_down(s, off);
    if (lane == 0) ((wid < NN) ? nx : ny)[row] = s;
}

__global__ void __launch_bounds__(256)
fused_kernel(const float* __restrict__ x, const float* __restrict__ y,
             const float* __restrict__ nx, const float* __restrict__ ny,
             float* __restrict__ out) {
    __shared__ __align__(16) short As[BM * LDP];
    __shared__ __align__(16) short Bs[BM * LDP];
    __shared__ float wsum[4];

    int p, ti, tj; float w;
    decode_tile(blockIdx.x, p, ti, tj, w);
    const float* P  = (p == 1) ? y  : x;
    const float* Q  = (p == 0) ? x  : y;
    const float* NA = (p == 1) ? ny : nx;
    const float* NB = (p == 0) ? nx : ny;

    const int t    = threadIdx.x;
    const int lane = t & 63;
    const int wvid = t >> 6;
    const int wm = wvid >> 1, wn = wvid & 1;

    f32x4 acc[4][4];
    #pragma unroll
    for (int m = 0; m < 4; ++m)
        #pragma unroll
        for (int n = 0; n < 4; ++n)
            acc[m][n] = (f32x4){0.f, 0.f, 0.f, 0.f};

    const int srow = t >> 3;
    const int scol = (t & 7) * 4;
    const size_t baseA = (size_t)(ti * BM) * DD;
    const size_t baseB = (size_t)(tj * BM) * DD;

    for (int kt = 0; kt < DD; kt += BK) {
        #pragma unroll
        for (int s = 0; s < 4; ++s) {
            int r = s * 32 + srow;
            float4 va = *(const float4*)(P + baseA + (size_t)r * DD + kt + scol);
            float4 vb = *(const float4*)(Q + baseB + (size_t)r * DD + kt + scol);
            short4v ha = { f2bf(va.x), f2bf(va.y), f2bf(va.z), f2bf(va.w) };
            short4v hb = { f2bf(vb.x), f2bf(vb.y), f2bf(vb.z), f2bf(vb.w) };
            *(short4v*)(&As[r * LDP + scol]) = ha;
            *(short4v*)(&Bs[r * LDP + scol]) = hb;
        }
        __syncthreads();

        short8v af[4], bfr[4];
        const int kc = (lane >> 4) * 8;
        #pragma unroll
        for (int m = 0; m < 4; ++m)
            af[m] = *(const short8v*)(&As[(wm * 64 + m * 16 + (lane & 15)) * LDP + kc]);
        #pragma unroll
        for (int n = 0; n < 4; ++n)
            bfr[n] = *(const short8v*)(&Bs[(wn * 64 + n * 16 + (lane & 15)) * LDP + kc]);
        #pragma unroll
        for (int m = 0; m < 4; ++m)
            #pragma unroll
            for (int n = 0; n < 4; ++n)
                acc[m][n] = __builtin_amdgcn_mfma_f32_16x16x32_bf16(af[m], bfr[n], acc[m][n], 0, 0, 0);
        __syncthreads();
    }

    float local = 0.f;
    #pragma unroll
    for (int m = 0; m < 4; ++m) {
        #pragma unroll
        for (int n = 0; n < 4; ++n) {
            #pragma unroll
            for (int r = 0; r < 4; ++r) {
                int row = wm * 64 + m * 16 + ((lane >> 4) << 2) + r;
                int col = wn * 64 + n * 16 + (lane & 15);
                int gr = ti * BM + row, gc = tj * BM + col;
                float g  = acc[m][n][r];
                float d2 = fmaxf(NA[gr] + NB[gc] - 2.f * g, 0.f);
                float e  = __expf(-d2);
                if (p == 2) {
                    float diff = g - ((gr == gc) ? 1.f : 0.f);
                    local += diff * diff - 2.f * e;
                } else {
                    local += w * e;
                }
            }
        }
    }
    #pragma unroll
    for (int off = 32; off > 0; off >>= 1) local += __shfl_down(local, off);
    if (lane == 0) wsum[wvid] = local;
    __syncthreads();
    if (t == 0) {
        float s = (wsum[0] + wsum[1]) + (wsum[2] + wsum[3]);
        atomicAdd(out, s * (1.f / ((float)NN * (float)NN)));
    }
}

extern "C" void kernel_launch(void* const* d_in, const int* in_sizes, int n_in,
                              void* d_out, int out_size, void* d_ws, size_t ws_size,
                              hipStream_t stream) {
    const float* x = (const float*)d_in[0];
    const float* y = (const float*)d_in[1];
    float* out = (float*)d_out;

    const size_t need = (size_t)2 * NN * DD * sizeof(ushort) + (size_t)2 * NN * sizeof(float);
    if (ws_size >= need) {
        ushort* bx = (ushort*)d_ws;
        ushort* by = bx + (size_t)NN * DD;
        float*  nx = (float*)(by + (size_t)NN * DD);
        float*  ny = nx + NN;
        prep_kernel<<<dim3(2048), dim3(256), 0, stream>>>(x, y, bx, by, nx, ny, out);
        fused10_kernel<<<dim3(NBLK), dim3(256), 0, stream>>>(bx, by, nx, ny, out);
    } else {
        hipMemsetAsync(d_out, 0, sizeof(float), stream);
        float* nx = (float*)d_ws;
        float* ny = nx + NN;
        norms_kernel<<<dim3(2048), dim3(256), 0, stream>>>(x, y, nx, ny);
        fused_kernel<<<dim3(NBLK), dim3(256), 0, stream>>>(x, y, nx, ny, out);
    }
}

// Round 11
// 71.145 us; speedup vs baseline: 1.1431x; 1.0719x over previous
//
#include <hip/hip_runtime.h>
#include <hip/hip_bf16.h>

#define NN 4096
#define DD 512

// ---- fused11: 128x128 tiles, 4 waves, BK=64, double buffer, counted vmcnt ----
#define BK8 64
#define NKT8 8                      // DD/BK8
#define TILES 32
#define TRI (TILES*(TILES+1)/2)     // 528
#define NBLK (TILES*TILES + 2*TRI)  // 2080 = 8 * 260

#define BM 128                      // fallback geometry
#define BK 32
#define LDP 40

typedef __attribute__((ext_vector_type(8))) short short8v;
typedef __attribute__((ext_vector_type(4))) short short4v;
typedef __attribute__((ext_vector_type(4))) float f32x4;

static __device__ __forceinline__ short f2bf(float f) {
    union { float f; unsigned u; } a; a.f = f;
    unsigned r = a.u + 0x7FFFu + ((a.u >> 16) & 1u);
    return (short)(r >> 16);
}

static __device__ __forceinline__ void stage16(const void* g, void* l) {
    __builtin_amdgcn_global_load_lds(
        (const __attribute__((address_space(1))) unsigned int*)g,
        (__attribute__((address_space(3))) unsigned int*)l, 16, 0, 0);
}

static __device__ __forceinline__ void decode_tile(int bid, int& p, int& ti, int& tj, float& w) {
    w = 1.f;
    if (bid < TILES * TILES) {
        p = 2; ti = bid >> 5; tj = bid & (TILES - 1);
    } else {
        int u = bid - TILES * TILES;
        p = 0;
        if (u >= TRI) { p = 1; u -= TRI; }
        int a = 0;
        while (u >= TILES - a) { u -= TILES - a; ++a; }
        ti = a; tj = a + u;
        if (ti != tj) w = 2.f;
    }
}

// ---------- prep: fp32 -> bf16 ws + row norms; also zeroes the output ----------
__global__ void prep_kernel(const float* __restrict__ x, const float* __restrict__ y,
                            ushort* __restrict__ bx, ushort* __restrict__ by,
                            float* __restrict__ nx, float* __restrict__ ny,
                            float* __restrict__ out) {
    if (blockIdx.x == 0 && threadIdx.x == 0) *out = 0.f;
    int wid  = (blockIdx.x * blockDim.x + threadIdx.x) >> 6;   // 0..8191
    int lane = threadIdx.x & 63;
    bool isx = wid < NN;
    const float* src = isx ? x : y;
    ushort* dst = isx ? bx : by;
    int row = wid & (NN - 1);
    const float4* p = (const float4*)(src + (size_t)row * DD);
    float s = 0.f;
    #pragma unroll
    for (int i = 0; i < 2; ++i) {
        float4 v = p[lane + 64 * i];
        s += v.x * v.x + v.y * v.y + v.z * v.z + v.w * v.w;
        short4v h = { f2bf(v.x), f2bf(v.y), f2bf(v.z), f2bf(v.w) };
        *(short4v*)(dst + (size_t)row * DD + 4 * (lane + 64 * i)) = h;
    }
    #pragma unroll
    for (int off = 32; off > 0; off >>= 1) s += __shfl_down(s, off);
    if (lane == 0) (isx ? nx : ny)[row] = s;
}

// ---------- fused11 ----------
// LDS per matrix per buffer: [128 rows][8 chunks of 16B] (128B rows), stored at
// pos = chunk ^ (row & 7)  — fused8's involution, measured 0 conflicts (r8).
__global__ void __launch_bounds__(256)
fused11_kernel(const ushort* __restrict__ bx, const ushort* __restrict__ by,
               const float* __restrict__ nx, const float* __restrict__ ny,
               float* __restrict__ out) {
    __shared__ __align__(16) ushort As[2][128 * 64];   // 2 x 16 KiB
    __shared__ __align__(16) ushort Bs[2][128 * 64];   // 2 x 16 KiB
    __shared__ float wsum[4];

    // bijective XCD swizzle: 2080 = 8 * 260 -> each XCD gets a contiguous chunk
    const int raw = blockIdx.x;
    const int bid = (raw & 7) * 260 + (raw >> 3);

    int p, ti, tj; float w;
    decode_tile(bid, p, ti, tj, w);

    const ushort* PB = (p == 1) ? by : bx;
    const ushort* QB = (p == 0) ? bx : by;
    const float*  NA = (p == 1) ? ny : nx;
    const float*  NB = (p == 0) ? nx : ny;

    const int t    = threadIdx.x;
    const int lane = t & 63;
    const int wv   = t >> 6;          // 0..3
    const int wm   = wv >> 1, wn = wv & 1;
    const int fr   = lane & 15;
    const int ch   = lane >> 4;       // 0..3

    const ushort* Ag = PB + (size_t)ti * 128 * DD;
    const ushort* Bg = QB + (size_t)tj * 128 * DD;

    // staging geometry (fused8, verified 0-conflict)
    const int srow = (lane >> 3);                            // 0..7
    const int sc8  = ((lane & 7) ^ ((lane >> 3) & 7)) * 8;   // inverse-swz source chunk

    f32x4 acc[4][4];
    #pragma unroll
    for (int m = 0; m < 4; ++m)
        #pragma unroll
        for (int n = 0; n < 4; ++n)
            acc[m][n] = (f32x4){0.f, 0.f, 0.f, 0.f};

#define STAGE11(kt, bb) do {                                                   \
        _Pragma("unroll")                                                      \
        for (int i_ = 0; i_ < 4; ++i_) {                                       \
            int row_ = i_ * 32 + wv * 8 + srow;                                \
            stage16(Ag + (size_t)row_ * DD + (kt) * BK8 + sc8,                 \
                    &As[bb][i_ * 2048 + wv * 512 + lane * 8]);                 \
            stage16(Bg + (size_t)row_ * DD + (kt) * BK8 + sc8,                 \
                    &Bs[bb][i_ * 2048 + wv * 512 + lane * 8]);                 \
        }                                                                      \
    } while (0)

    // prologue: tile 0 in flight into buffer 0
    STAGE11(0, 0);

    #pragma unroll
    for (int kt = 0; kt < NKT8; ++kt) {
        const int cur = kt & 1;
        // 1) issue next tile into the other buffer (its readers were certified
        //    done by the trailing barrier of step kt-1), then certify tile kt
        if (kt + 1 < NKT8) {
            STAGE11(kt + 1, cur ^ 1);
            asm volatile("s_waitcnt vmcnt(8)" ::: "memory");   // tile kt landed
        } else {
            asm volatile("s_waitcnt vmcnt(0)" ::: "memory");
        }
        __builtin_amdgcn_s_barrier();        // all waves certified -> tile kt readable

        // 2) read the 16 fragments of tile kt
        short8v af[2][4], bf[2][4];
        #pragma unroll
        for (int kk = 0; kk < 2; ++kk) {
            const int pa = ((kk * 4 + ch) ^ (fr & 7)) * 8;   // swizzled chunk
            #pragma unroll
            for (int m = 0; m < 4; ++m)
                af[kk][m] = *(const short8v*)&As[cur][(wm * 64 + m * 16 + fr) * 64 + pa];
            #pragma unroll
            for (int n = 0; n < 4; ++n)
                bf[kk][n] = *(const short8v*)&Bs[cur][(wn * 64 + n * 16 + fr) * 64 + pa];
        }

        // 3) MFMA cluster (32 MFMA); next-tile loads still in flight underneath
        #pragma unroll
        for (int kk = 0; kk < 2; ++kk)
            #pragma unroll
            for (int m = 0; m < 4; ++m)
                #pragma unroll
                for (int n = 0; n < 4; ++n)
                    acc[m][n] = __builtin_amdgcn_mfma_f32_16x16x32_bf16(
                        af[kk][m], bf[kk][n], acc[m][n], 0, 0, 0);

        // 4) all waves done reading buffer cur -> step kt+1 may overwrite it
        __builtin_amdgcn_s_barrier();
    }
#undef STAGE11

    // ---- epilogue (fused8's verified layout) ----
    float nbv[4];
    #pragma unroll
    for (int n = 0; n < 4; ++n)
        nbv[n] = NB[tj * 128 + wn * 64 + n * 16 + fr];
    const int rbase = ((lane >> 4) << 2);

    float local = 0.f;
    #pragma unroll
    for (int m = 0; m < 4; ++m) {
        float4 na4 = *(const float4*)(&NA[ti * 128 + wm * 64 + m * 16 + rbase]);
        float nav[4] = { na4.x, na4.y, na4.z, na4.w };
        #pragma unroll
        for (int n = 0; n < 4; ++n) {
            #pragma unroll
            for (int rr = 0; rr < 4; ++rr) {
                int gr = ti * 128 + wm * 64 + m * 16 + rbase + rr;
                int gc = tj * 128 + wn * 64 + n * 16 + fr;
                float g  = acc[m][n][rr];
                float d2 = fmaxf(nav[rr] + nbv[n] - 2.f * g, 0.f);
                float e  = __expf(-d2);
                if (p == 2) {
                    float diff = g - ((gr == gc) ? 1.f : 0.f);
                    local += diff * diff - 2.f * e;
                } else {
                    local += w * e;
                }
            }
        }
    }
    #pragma unroll
    for (int off = 32; off > 0; off >>= 1) local += __shfl_down(local, off);
    if (lane == 0) wsum[wv] = local;
    __syncthreads();
    if (t == 0) {
        float s = (wsum[0] + wsum[1]) + (wsum[2] + wsum[3]);
        atomicAdd(out, s * (1.f / ((float)NN * (float)NN)));
    }
}

// ---------- fallback path (round-1, used only if ws too small) ----------
__global__ void norms_kernel(const float* __restrict__ x, const float* __restrict__ y,
                             float* __restrict__ nx, float* __restrict__ ny) {
    int wid  = (blockIdx.x * blockDim.x + threadIdx.x) >> 6;
    int lane = threadIdx.x & 63;
    const float* src = (wid < NN) ? x : y;
    int row = wid & (NN - 1);
    const float4* p = (const float4*)(src + (size_t)row * DD);
    float s = 0.f;
    #pragma unroll
    for (int i = 0; i < 2; ++i) {
        float4 v = p[lane + 64 * i];
        s += v.x * v.x + v.y * v.y + v.z * v.z + v.w * v.w;
    }
    #pragma unroll
    for (int off = 32; off > 0; off >>= 1) s += __shfl_down(s, off);
    if (lane == 0) ((wid < NN) ? nx : ny)[row] = s;
}

__global__ void __launch_bounds__(256)
fused_kernel(const float* __restrict__ x, const float* __restrict__ y,
             const float* __restrict__ nx, const float* __restrict__ ny,
             float* __restrict__ out) {
    __shared__ __align__(16) short As[BM * LDP];
    __shared__ __align__(16) short Bs[BM * LDP];
    __shared__ float wsum[4];

    int p, ti, tj; float w;
    decode_tile(blockIdx.x, p, ti, tj, w);
    const float* P  = (p == 1) ? y  : x;
    const float* Q  = (p == 0) ? x  : y;
    const float* NA = (p == 1) ? ny : nx;
    const float* NB = (p == 0) ? nx : ny;

    const int t    = threadIdx.x;
    const int lane = t & 63;
    const int wvid = t >> 6;
    const int wm = wvid >> 1, wn = wvid & 1;

    f32x4 acc[4][4];
    #pragma unroll
    for (int m = 0; m < 4; ++m)
        #pragma unroll
        for (int n = 0; n < 4; ++n)
            acc[m][n] = (f32x4){0.f, 0.f, 0.f, 0.f};

    const int srow = t >> 3;
    const int scol = (t & 7) * 4;
    const size_t baseA = (size_t)(ti * BM) * DD;
    const size_t baseB = (size_t)(tj * BM) * DD;

    for (int kt = 0; kt < DD; kt += BK) {
        #pragma unroll
        for (int s = 0; s < 4; ++s) {
            int r = s * 32 + srow;
            float4 va = *(const float4*)(P + baseA + (size_t)r * DD + kt + scol);
            float4 vb = *(const float4*)(Q + baseB + (size_t)r * DD + kt + scol);
            short4v ha = { f2bf(va.x), f2bf(va.y), f2bf(va.z), f2bf(va.w) };
            short4v hb = { f2bf(vb.x), f2bf(vb.y), f2bf(vb.z), f2bf(vb.w) };
            *(short4v*)(&As[r * LDP + scol]) = ha;
            *(short4v*)(&Bs[r * LDP + scol]) = hb;
        }
        __syncthreads();

        short8v af[4], bfr[4];
        const int kc = (lane >> 4) * 8;
        #pragma unroll
        for (int m = 0; m < 4; ++m)
            af[m] = *(const short8v*)(&As[(wm * 64 + m * 16 + (lane & 15)) * LDP + kc]);
        #pragma unroll
        for (int n = 0; n < 4; ++n)
            bfr[n] = *(const short8v*)(&Bs[(wn * 64 + n * 16 + (lane & 15)) * LDP + kc]);
        #pragma unroll
        for (int m = 0; m < 4; ++m)
            #pragma unroll
            for (int n = 0; n < 4; ++n)
                acc[m][n] = __builtin_amdgcn_mfma_f32_16x16x32_bf16(af[m], bfr[n], acc[m][n], 0, 0, 0);
        __syncthreads();
    }

    float local = 0.f;
    #pragma unroll
    for (int m = 0; m < 4; ++m) {
        #pragma unroll
        for (int n = 0; n < 4; ++n) {
            #pragma unroll
            for (int r = 0; r < 4; ++r) {
                int row = wm * 64 + m * 16 + ((lane >> 4) << 2) + r;
                int col = wn * 64 + n * 16 + (lane & 15);
                int gr = ti * BM + row, gc = tj * BM + col;
                float g  = acc[m][n][r];
                float d2 = fmaxf(NA[gr] + NB[gc] - 2.f * g, 0.f);
                float e  = __expf(-d2);
                if (p == 2) {
                    float diff = g - ((gr == gc) ? 1.f : 0.f);
                    local += diff * diff - 2.f * e;
                } else {
                    local += w * e;
                }
            }
        }
    }
    #pragma unroll
    for (int off = 32; off > 0; off >>= 1) local += __shfl_down(local, off);
    if (lane == 0) wsum[wvid] = local;
    __syncthreads();
    if (t == 0) {
        float s = (wsum[0] + wsum[1]) + (wsum[2] + wsum[3]);
        atomicAdd(out, s * (1.f / ((float)NN * (float)NN)));
    }
}

extern "C" void kernel_launch(void* const* d_in, const int* in_sizes, int n_in,
                              void* d_out, int out_size, void* d_ws, size_t ws_size,
                              hipStream_t stream) {
    const float* x = (const float*)d_in[0];
    const float* y = (const float*)d_in[1];
    float* out = (float*)d_out;

    const size_t need = (size_t)2 * NN * DD * sizeof(ushort) + (size_t)2 * NN * sizeof(float);
    if (ws_size >= need) {
        ushort* bx = (ushort*)d_ws;
        ushort* by = bx + (size_t)NN * DD;
        float*  nx = (float*)(by + (size_t)NN * DD);
        float*  ny = nx + NN;
        prep_kernel<<<dim3(2048), dim3(256), 0, stream>>>(x, y, bx, by, nx, ny, out);
        fused11_kernel<<<dim3(NBLK), dim3(256), 0, stream>>>(bx, by, nx, ny, out);
    } else {
        hipMemsetAsync(d_out, 0, sizeof(float), stream);
        float* nx = (float*)d_ws;
        float* ny = nx + NN;
        norms_kernel<<<dim3(2048), dim3(256), 0, stream>>>(x, y, nx, ny);
        fused_kernel<<<dim3(NBLK), dim3(256), 0, stream>>>(x, y, nx, ny, out);
    }
}